// Round 3
// baseline (333.051 us; speedup 1.0000x reference)
//
#include <hip/hip_runtime.h>
#include <hip/hip_bf16.h>

// Multihead cross-attention, B=2, LQ=LK=4096, D=768, H=8, dh=96.
// Pipeline: Wt transpose+bf16 -> QKV projection GEMMs (bf16 MFMA) -> flash attn.
// Attn: swapped-QK^T (S^T, q lane-local softmax), 64 q/wave, KBLK=64,
//       global_load_lds dbuf staging (linear K, XOR-swizzled V), defer-rescale.

typedef __bf16 bf16x8 __attribute__((ext_vector_type(8)));
typedef __bf16 bf16x4 __attribute__((ext_vector_type(4)));
typedef float  f32x4  __attribute__((ext_vector_type(4)));

#define DM   768
#define NH   8
#define HD   96
#define SEQ  4096
#define BATCH 2
#define WELEM (DM*DM)   // 589824

#define GLDS16(gp, lp) __builtin_amdgcn_global_load_lds( \
    (const __attribute__((address_space(1))) void*)(gp), \
    (__attribute__((address_space(3))) void*)(lp), 16, 0, 0)

// ---------------- W transpose + f32->bf16 (one launch, 3 matrices) -------------
__global__ __launch_bounds__(256) void transpose_w3(
    const float* __restrict__ Wq, const float* __restrict__ Wk, const float* __restrict__ Wv,
    __bf16* __restrict__ Tq, __bf16* __restrict__ Tk, __bf16* __restrict__ Tv)
{
    int tid = blockIdx.x * 256 + threadIdx.x;   // 3*589824 total
    int which = tid / WELEM;                    // uniform per block (2304 blocks each)
    int e = tid - which * WELEM;
    int k = e / DM, n = e - k * DM;             // W[k][n], read coalesced
    const float* W = (which == 0) ? Wq : (which == 1) ? Wk : Wv;
    __bf16* T      = (which == 0) ? Tq : (which == 1) ? Tk : Tv;
    T[n * DM + k] = (__bf16)W[e];
}

// ---------------- projection GEMM: Y = X @ W  (X f32 [8192][768], Wt bf16 [n][k]) ----
// mode 0: Y[b][h][l][d] = acc*scale   (Q: scale=log2e/sqrt(96); K: scale=1)
// mode 1: Y[b][h][d][l] = acc         (V transposed)
__global__ __launch_bounds__(256) void proj_gemm(
    const float* __restrict__ X, const __bf16* __restrict__ Wt,
    __bf16* __restrict__ Y, int mode, float scale)
{
    __shared__ __bf16 Xs[64][40];   // +8 pad: row stride 80B -> 2-way max bank pattern
    __shared__ __bf16 Ws[64][40];

    const int t = threadIdx.x;
    const int l = t & 63;
    const int w = t >> 6;
    const int wm = w >> 1, wn = w & 1;
    const int m0 = blockIdx.x * 64;
    const int n0 = blockIdx.y * 64;

    const int srow = t >> 2;
    const int scol = (t & 3) * 8;

    f32x4 acc[2][2] = {};

    for (int kt = 0; kt < DM / 32; ++kt) {
        const int k0 = kt * 32;
        __syncthreads();
        {   // stage X tile 64x32 (f32 -> bf16)
            const float* src = X + (size_t)(m0 + srow) * DM + k0 + scol;
            float4 lo = *reinterpret_cast<const float4*>(src);
            float4 hi = *reinterpret_cast<const float4*>(src + 4);
            bf16x8 v;
            v[0]=(__bf16)lo.x; v[1]=(__bf16)lo.y; v[2]=(__bf16)lo.z; v[3]=(__bf16)lo.w;
            v[4]=(__bf16)hi.x; v[5]=(__bf16)hi.y; v[6]=(__bf16)hi.z; v[7]=(__bf16)hi.w;
            *reinterpret_cast<bf16x8*>(&Xs[srow][scol]) = v;
        }
        {   // stage Wt tile 64(n)x32(k), already bf16
            const __bf16* src = Wt + (size_t)(n0 + srow) * DM + k0 + scol;
            *reinterpret_cast<bf16x8*>(&Ws[srow][scol]) =
                *reinterpret_cast<const bf16x8*>(src);
        }
        __syncthreads();

        bf16x8 a[2], b[2];
        #pragma unroll
        for (int ms = 0; ms < 2; ++ms)
            a[ms] = *reinterpret_cast<const bf16x8*>(&Xs[wm*32 + ms*16 + (l & 15)][(l >> 4) * 8]);
        #pragma unroll
        for (int ns = 0; ns < 2; ++ns)
            b[ns] = *reinterpret_cast<const bf16x8*>(&Ws[wn*32 + ns*16 + (l & 15)][(l >> 4) * 8]);
        #pragma unroll
        for (int ms = 0; ms < 2; ++ms)
            #pragma unroll
            for (int ns = 0; ns < 2; ++ns)
                acc[ms][ns] = __builtin_amdgcn_mfma_f32_16x16x32_bf16(a[ms], b[ns], acc[ms][ns], 0, 0, 0);
    }

    // epilogue: D layout col=lane&15, row=4*(lane>>4)+r  [m89]
    #pragma unroll
    for (int ms = 0; ms < 2; ++ms) {
        #pragma unroll
        for (int ns = 0; ns < 2; ++ns) {
            const int col = n0 + wn*32 + ns*16 + (l & 15);
            const int h = col / HD, d = col - h * HD;
            const int row_base = m0 + wm*32 + ms*16 + (l >> 4) * 4;
            if (mode == 0) {
                #pragma unroll
                for (int r = 0; r < 4; ++r) {
                    int row = row_base + r;
                    int b_ = row >> 12, q = row & (SEQ - 1);
                    Y[(((size_t)(b_ * NH + h) * SEQ) + q) * HD + d] =
                        (__bf16)(acc[ms][ns][r] * scale);
                }
            } else {
                int b_ = row_base >> 12, kq = row_base & (SEQ - 1);
                bf16x4 v;
                #pragma unroll
                for (int r = 0; r < 4; ++r) v[r] = (__bf16)acc[ms][ns][r];
                *reinterpret_cast<bf16x4*>(
                    &Y[((size_t)(b_ * NH + h) * HD + d) * SEQ + kq]) = v;
            }
        }
    }
}

// ---------------- flash attention (swapped QK^T, 64 q/wave) ----------------
// grid (LQ/256, B*H), 4 waves x 64 q-rows, KBLK=64.
// Staging: global_load_lds width-16, double-buffered.
//   Ks [64][96] linear (reads conflict-free: pos = 16((ln+c)&1)+4g).
//   Vs [96][64] with 16B-chunk swizzle cc ^= (row&7) on source AND read.
// Q prescaled by log2e/sqrt(96). S^T: lane holds S[k=16ks+4g+r][q=ln+16f].
__global__ __launch_bounds__(256, 1) void attn_kernel(
    const __bf16* __restrict__ Q, const __bf16* __restrict__ K,
    const __bf16* __restrict__ Vt, float* __restrict__ out)
{
    __shared__ __bf16 Ks[2][64][96];   // 24576 B
    __shared__ __bf16 Vs[2][96][64];   // 24576 B
    __shared__ __bf16 Pl[4][64][32];   // 16384 B  (total exactly 64 KiB)

    const int t = threadIdx.x;
    const int l = t & 63;
    const int w = t >> 6;
    const int g = l >> 4;            // 16-lane group id (0..3)
    const int ln = l & 15;
    const int bh = blockIdx.y;
    const int b = bh >> 3, h = bh & 7;
    const int q0 = blockIdx.x * 256;

    const size_t base = (size_t)bh * SEQ * HD;
    const __bf16* Kg = K + base;
    const __bf16* Vg = Vt + base;

    // staging geometry: 12 K-chunks + 12 V-chunks of 1 KiB, 3+3 per wave
    const __bf16* kg[3]; const __bf16* vg[3];
    unsigned ldso[3];
    #pragma unroll
    for (int i = 0; i < 3; ++i) {
        const int id = (3 * w + i) * 64 + l;
        const int kr = id / 12, kc_ = id - kr * 12;
        kg[i] = Kg + (size_t)kr * HD + kc_ * 8;
        const int vr = id >> 3, vc = id & 7;
        vg[i] = Vg + (size_t)vr * SEQ + 8 * (vc ^ (vr & 7));   // inverse-swizzled source
        ldso[i] = (3 * w + i) * 1024;                          // uniform per wave
    }

    // Q B-fragments in registers: B-frag n=ln, k=8g+e  (4 f x 3 c)
    bf16x8 qb[4][3];
    #pragma unroll
    for (int f = 0; f < 4; ++f) {
        const int q = q0 + w * 64 + 16 * f + ln;
        #pragma unroll
        for (int c = 0; c < 3; ++c)
            qb[f][c] = *reinterpret_cast<const bf16x8*>(
                &Q[base + (size_t)q * HD + c * 32 + g * 8]);
    }

    f32x4 acc[4][6] = {};
    float m_r[4], l_r[4];
    #pragma unroll
    for (int f = 0; f < 4; ++f) { m_r[f] = -1e30f; l_r[f] = 0.f; }

    // prologue: stage tile 0 -> buf 0
    #pragma unroll
    for (int i = 0; i < 3; ++i) GLDS16(kg[i], (char*)&Ks[0][0][0] + ldso[i]);
    #pragma unroll
    for (int i = 0; i < 3; ++i) GLDS16(vg[i], (char*)&Vs[0][0][0] + ldso[i]);
    __syncthreads();

    const int NT = SEQ / 64;
    for (int kt = 0; kt < NT; ++kt) {
        const int cur = kt & 1, nxt = cur ^ 1;

        // issue next-tile staging EARLY (async; drains at the end-of-iter barrier)
        if (kt + 1 < NT) {
            #pragma unroll
            for (int i = 0; i < 3; ++i)
                GLDS16(kg[i] + (size_t)(kt + 1) * 64 * HD, (char*)&Ks[nxt][0][0] + ldso[i]);
            #pragma unroll
            for (int i = 0; i < 3; ++i)
                GLDS16(vg[i] + (size_t)(kt + 1) * 64, (char*)&Vs[nxt][0][0] + ldso[i]);
        }

        // ---- QK^T: S^T[k][q], A=K(m=k), B=Q(n=q) ----
        f32x4 s[4][4] = {};   // [f][ks]
        #pragma unroll
        for (int ks = 0; ks < 4; ++ks) {
            bf16x8 ka[3];
            #pragma unroll
            for (int c = 0; c < 3; ++c)
                ka[c] = *reinterpret_cast<const bf16x8*>(
                    &Ks[cur][ks * 16 + ln][c * 32 + g * 8]);
            #pragma unroll
            for (int f = 0; f < 4; ++f)
                #pragma unroll
                for (int c = 0; c < 3; ++c)
                    s[f][ks] = __builtin_amdgcn_mfma_f32_16x16x32_bf16(
                        ka[c], qb[f][c], s[f][ks], 0, 0, 0);
        }

        // ---- online softmax: q lane-local (q = ln + 16f), replicated over g ----
        float tm[4];
        #pragma unroll
        for (int f = 0; f < 4; ++f) {
            float v = s[f][0][0];
            #pragma unroll
            for (int ks = 0; ks < 4; ++ks)
                #pragma unroll
                for (int r = 0; r < 4; ++r) v = fmaxf(v, s[f][ks][r]);
            v = fmaxf(v, __shfl_xor(v, 16));
            v = fmaxf(v, __shfl_xor(v, 32));
            tm[f] = v;
        }
        bool grow = (tm[0] > m_r[0]) | (tm[1] > m_r[1]) |
                    (tm[2] > m_r[2]) | (tm[3] > m_r[3]);
        if (__any(grow)) {   // exact defer-rescale: alpha==1 when no growth
            #pragma unroll
            for (int f = 0; f < 4; ++f) {
                float mn = fmaxf(m_r[f], tm[f]);
                float a  = __builtin_amdgcn_exp2f(m_r[f] - mn);
                m_r[f] = mn;
                l_r[f] *= a;
                float ab[4];
                #pragma unroll
                for (int r = 0; r < 4; ++r) ab[r] = __shfl(a, g * 4 + r);
                #pragma unroll
                for (int ns = 0; ns < 6; ++ns)
                    #pragma unroll
                    for (int r = 0; r < 4; ++r) acc[f][ns][r] *= ab[r];
            }
        }
        // p = exp2(s - m) in place; row-sum
        #pragma unroll
        for (int f = 0; f < 4; ++f) {
            const float mm = m_r[f];
            float ps = 0.f;
            #pragma unroll
            for (int ks = 0; ks < 4; ++ks)
                #pragma unroll
                for (int r = 0; r < 4; ++r) {
                    float p = __builtin_amdgcn_exp2f(s[f][ks][r] - mm);
                    s[f][ks][r] = p;
                    ps += p;
                }
            ps += __shfl_xor(ps, 16);
            ps += __shfl_xor(ps, 32);
            l_r[f] += ps;
        }

        // ---- PV per 32-k chunk: P through per-wave LDS, A=P(m=q), B=V(n=d) ----
        #pragma unroll
        for (int kc = 0; kc < 2; ++kc) {
            #pragma unroll
            for (int f = 0; f < 4; ++f) {
                bf16x4 p0, p1;
                #pragma unroll
                for (int r = 0; r < 4; ++r) {
                    p0[r] = (__bf16)s[f][2 * kc][r];
                    p1[r] = (__bf16)s[f][2 * kc + 1][r];
                }
                *reinterpret_cast<bf16x4*>(&Pl[w][16 * f + ln][4 * g])      = p0;
                *reinterpret_cast<bf16x4*>(&Pl[w][16 * f + ln][16 + 4 * g]) = p1;
            }
            bf16x8 pa[4];
            #pragma unroll
            for (int f = 0; f < 4; ++f)
                pa[f] = *reinterpret_cast<const bf16x8*>(&Pl[w][16 * f + ln][8 * g]);
            #pragma unroll
            for (int ns = 0; ns < 6; ++ns) {
                const int cw = (4 * kc + g) ^ (ln & 7);   // swizzled 16B-chunk read
                bf16x8 vb = *reinterpret_cast<const bf16x8*>(
                    &Vs[cur][ns * 16 + ln][8 * cw]);
                #pragma unroll
                for (int f = 0; f < 4; ++f)
                    acc[f][ns] = __builtin_amdgcn_mfma_f32_16x16x32_bf16(
                        pa[f], vb, acc[f][ns], 0, 0, 0);
            }
        }

        __syncthreads();   // drains glds (vmcnt 0) -> nxt buffer ready; guards reuse
    }

    // epilogue: acc layout col=ln=d, row=4g+r=q-local(16f+4g+r)
    #pragma unroll
    for (int f = 0; f < 4; ++f) {
        float inv[4];
        #pragma unroll
        for (int r = 0; r < 4; ++r)
            inv[r] = 1.0f / __shfl(l_r[f], g * 4 + r);
        #pragma unroll
        for (int ns = 0; ns < 6; ++ns)
            #pragma unroll
            for (int r = 0; r < 4; ++r) {
                const int q = q0 + w * 64 + 16 * f + 4 * g + r;
                out[((size_t)(b * SEQ + q)) * DM + h * HD + ns * 16 + ln] =
                    acc[f][ns][r] * inv[r];
            }
    }
}

extern "C" void kernel_launch(void* const* d_in, const int* in_sizes, int n_in,
                              void* d_out, int out_size, void* d_ws, size_t ws_size,
                              hipStream_t stream) {
    const float* hidden = (const float*)d_in[0];
    const float* kv     = (const float*)d_in[1];
    const float* Wq     = (const float*)d_in[2];
    const float* Wk     = (const float*)d_in[3];
    const float* Wv     = (const float*)d_in[4];
    float* out = (float*)d_out;

    // workspace layout (bf16): Wt_q, Wt_k, Wt_v, Q, K, Vt  (~41.3 MB total)
    __bf16* Wt_q = (__bf16*)d_ws;
    __bf16* Wt_k = Wt_q + WELEM;
    __bf16* Wt_v = Wt_k + WELEM;
    __bf16* Qb   = Wt_v + WELEM;
    __bf16* Kb   = Qb + (size_t)BATCH * NH * SEQ * HD;
    __bf16* Vtb  = Kb + (size_t)BATCH * NH * SEQ * HD;

    transpose_w3<<<3 * (WELEM / 256), 256, 0, stream>>>(Wq, Wk, Wv, Wt_q, Wt_k, Wt_v);

    const float qscale = 0.10206207261596575f * 1.4426950408889634f; // 1/sqrt(96)*log2(e)
    dim3 pgrid(BATCH * SEQ / 64, DM / 64);
    proj_gemm<<<pgrid, 256, 0, stream>>>(hidden, Wt_q, Qb, 0, qscale);
    proj_gemm<<<pgrid, 256, 0, stream>>>(kv,     Wt_k, Kb, 0, 1.0f);
    proj_gemm<<<pgrid, 256, 0, stream>>>(kv,     Wt_v, Vtb, 1, 1.0f);

    attn_kernel<<<dim3(SEQ / 256, BATCH * NH), 256, 0, stream>>>(Qb, Kb, Vtb, out);
}

// Round 4
// 222.724 us; speedup vs baseline: 1.4953x; 1.4953x over previous
//
#include <hip/hip_runtime.h>
#include <hip/hip_bf16.h>

// Multihead cross-attention, B=2, LQ=LK=4096, D=768, H=8, dh=96.
// Pipeline: Wt transpose+bf16 -> QKV projection GEMMs (bf16 MFMA) -> flash attn.
// Attn: 32x32x16 MFMA, swapped QK^T (q lane-local), P in-register via
//       cvt_pk+permlane32_swap (no P LDS), glds swizzled dbuf staging,
//       defer-rescale THR=8, XCD-chunked block swizzle.

typedef __bf16 bf16x8 __attribute__((ext_vector_type(8)));
typedef __bf16 bf16x4 __attribute__((ext_vector_type(4)));
typedef float  f32x4  __attribute__((ext_vector_type(4)));
typedef float  f32x16 __attribute__((ext_vector_type(16)));
typedef unsigned u32x4 __attribute__((ext_vector_type(4)));

#define DM   768
#define NH   8
#define HD   96
#define SEQ  4096
#define BATCH 2
#define WELEM (DM*DM)   // 589824

#define GLDS16(gp, lp) __builtin_amdgcn_global_load_lds( \
    (const __attribute__((address_space(1))) void*)(gp), \
    (__attribute__((address_space(3))) void*)(lp), 16, 0, 0)

// ---------------- W transpose + f32->bf16 (one launch, 3 matrices) -------------
__global__ __launch_bounds__(256) void transpose_w3(
    const float* __restrict__ Wq, const float* __restrict__ Wk, const float* __restrict__ Wv,
    __bf16* __restrict__ Tq, __bf16* __restrict__ Tk, __bf16* __restrict__ Tv)
{
    int tid = blockIdx.x * 256 + threadIdx.x;   // 3*589824 total
    int which = tid / WELEM;                    // uniform per block (2304 blocks each)
    int e = tid - which * WELEM;
    int k = e / DM, n = e - k * DM;             // W[k][n], read coalesced
    const float* W = (which == 0) ? Wq : (which == 1) ? Wk : Wv;
    __bf16* T      = (which == 0) ? Tq : (which == 1) ? Tk : Tv;
    T[n * DM + k] = (__bf16)W[e];
}

// ---------------- projection GEMM: Y = X @ W  (X f32 [8192][768], Wt bf16 [n][k]) ----
// mode 0: Y[b][h][l][d] = acc*scale   (Q: scale=log2e/sqrt(96); K: scale=1)
// mode 1: Y[b][h][d][l] = acc         (V transposed)
__global__ __launch_bounds__(256) void proj_gemm(
    const float* __restrict__ X, const __bf16* __restrict__ Wt,
    __bf16* __restrict__ Y, int mode, float scale)
{
    __shared__ __bf16 Xs[64][40];   // +8 pad: row stride 80B -> 2-way max bank pattern
    __shared__ __bf16 Ws[64][40];

    const int t = threadIdx.x;
    const int l = t & 63;
    const int w = t >> 6;
    const int wm = w >> 1, wn = w & 1;
    const int m0 = blockIdx.x * 64;
    const int n0 = blockIdx.y * 64;

    const int srow = t >> 2;
    const int scol = (t & 3) * 8;

    f32x4 acc[2][2] = {};

    for (int kt = 0; kt < DM / 32; ++kt) {
        const int k0 = kt * 32;
        __syncthreads();
        {   // stage X tile 64x32 (f32 -> bf16)
            const float* src = X + (size_t)(m0 + srow) * DM + k0 + scol;
            float4 lo = *reinterpret_cast<const float4*>(src);
            float4 hi = *reinterpret_cast<const float4*>(src + 4);
            bf16x8 v;
            v[0]=(__bf16)lo.x; v[1]=(__bf16)lo.y; v[2]=(__bf16)lo.z; v[3]=(__bf16)lo.w;
            v[4]=(__bf16)hi.x; v[5]=(__bf16)hi.y; v[6]=(__bf16)hi.z; v[7]=(__bf16)hi.w;
            *reinterpret_cast<bf16x8*>(&Xs[srow][scol]) = v;
        }
        {   // stage Wt tile 64(n)x32(k), already bf16
            const __bf16* src = Wt + (size_t)(n0 + srow) * DM + k0 + scol;
            *reinterpret_cast<bf16x8*>(&Ws[srow][scol]) =
                *reinterpret_cast<const bf16x8*>(src);
        }
        __syncthreads();

        bf16x8 a[2], b[2];
        #pragma unroll
        for (int ms = 0; ms < 2; ++ms)
            a[ms] = *reinterpret_cast<const bf16x8*>(&Xs[wm*32 + ms*16 + (l & 15)][(l >> 4) * 8]);
        #pragma unroll
        for (int ns = 0; ns < 2; ++ns)
            b[ns] = *reinterpret_cast<const bf16x8*>(&Ws[wn*32 + ns*16 + (l & 15)][(l >> 4) * 8]);
        #pragma unroll
        for (int ms = 0; ms < 2; ++ms)
            #pragma unroll
            for (int ns = 0; ns < 2; ++ns)
                acc[ms][ns] = __builtin_amdgcn_mfma_f32_16x16x32_bf16(a[ms], b[ns], acc[ms][ns], 0, 0, 0);
    }

    // epilogue: D layout col=lane&15, row=4*(lane>>4)+r  [m89]
    #pragma unroll
    for (int ms = 0; ms < 2; ++ms) {
        #pragma unroll
        for (int ns = 0; ns < 2; ++ns) {
            const int col = n0 + wn*32 + ns*16 + (l & 15);
            const int h = col / HD, d = col - h * HD;
            const int row_base = m0 + wm*32 + ms*16 + (l >> 4) * 4;
            if (mode == 0) {
                #pragma unroll
                for (int r = 0; r < 4; ++r) {
                    int row = row_base + r;
                    int b_ = row >> 12, q = row & (SEQ - 1);
                    Y[(((size_t)(b_ * NH + h) * SEQ) + q) * HD + d] =
                        (__bf16)(acc[ms][ns][r] * scale);
                }
            } else {
                int b_ = row_base >> 12, kq = row_base & (SEQ - 1);
                bf16x4 v;
                #pragma unroll
                for (int r = 0; r < 4; ++r) v[r] = (__bf16)acc[ms][ns][r];
                *reinterpret_cast<bf16x4*>(
                    &Y[((size_t)(b_ * NH + h) * HD + d) * SEQ + kq]) = v;
            }
        }
    }
}

// ---------------- flash attention: 32x32x16 MFMA, P in registers ----------------
// 1D grid 512 blocks (XCD-chunked swizzle), 4 waves x 32 q-rows, KBLK=64.
// S^T = mfma(K, Q): D col = q = lane&31 (lane-local softmax),
//                   row = kappa = (r&3)+8*(r>>2)+4*(lane>>5).
// PV: ctx = mfma(P, V): A=P built in-register (cvt_pk + permlane32_swap).
__global__ __launch_bounds__(256, 2) void attn_kernel(
    const __bf16* __restrict__ Q, const __bf16* __restrict__ K,
    const __bf16* __restrict__ Vt, float* __restrict__ out)
{
    __shared__ __bf16 Ks[2][64][128];  // 2x16KB, rows padded 96->128 (16 chunks, XOR r&7)
    __shared__ __bf16 Vs[2][96][64];   // 2x12KB, 8 chunks/row, XOR d&7

    const int t = threadIdx.x;
    const int l = t & 63;
    const int w = t >> 6;
    const int lh = l >> 5;            // lane half (0/1)
    const int c31 = l & 31;

    // XCD-chunked swizzle: 512 blocks, XCD x owns bh {2x, 2x+1}
    const int swz = (blockIdx.x & 7) * 64 + (blockIdx.x >> 3);
    const int bh = swz >> 5;          // 0..15
    const int qb = swz & 31;          // 0..31
    const int b = bh >> 3, hd = bh & 7;
    const int q0 = qb * 128 + w * 32;

    const size_t base = (size_t)bh * SEQ * HD;
    const __bf16* Kg = K + base;
    const __bf16* Vg = Vt + base;

    // staging geometry: K tile 64 rows x 16 chunks (12 valid, 4 dup->chunk0),
    //                   V tile 96 rows x 8 chunks. glds dest = uniform base + 16*lane.
    size_t ksrc[4], vsrc[3];
    unsigned kdst[4], vdst[3];
    #pragma unroll
    for (int j = 0; j < 4; ++j) {
        const int cid = (w * 4 + j) * 64 + l;        // 0..1023
        const int r = cid >> 4, cc = cid & 15;
        int cs = cc ^ (r & 7); if (cs >= 12) cs = 0; // pad chunks -> dup chunk 0 (L2 hit)
        ksrc[j] = (size_t)r * HD + cs * 8;
        kdst[j] = (w * 4 + j) * 1024;
    }
    #pragma unroll
    for (int j = 0; j < 3; ++j) {
        const int cid = (w * 3 + j) * 64 + l;        // 0..767
        const int d = cid >> 3, cc = cid & 7;
        const int cs = cc ^ (d & 7);
        vsrc[j] = (size_t)d * SEQ + cs * 8;
        vdst[j] = (w * 3 + j) * 1024;
    }

    // Q B-fragments (col = q = lane&31, k(d) = 16*st + 8*lh + e), in registers
    bf16x8 qb_[6];
    #pragma unroll
    for (int st = 0; st < 6; ++st)
        qb_[st] = *reinterpret_cast<const bf16x8*>(
            &Q[base + (size_t)(q0 + c31) * HD + st * 16 + 8 * lh]);

    f32x16 acc[3] = {};
    float m_r = -1e30f, l_r = 0.f;

    // prologue: stage tile 0 -> buf 0
    #pragma unroll
    for (int j = 0; j < 4; ++j) GLDS16(Kg + ksrc[j], (char*)Ks + kdst[j]);
    #pragma unroll
    for (int j = 0; j < 3; ++j) GLDS16(Vg + vsrc[j], (char*)Vs + vdst[j]);
    __syncthreads();

    const int NT = SEQ / 64;
    for (int kt = 0; kt < NT; ++kt) {
        const int cur = kt & 1;

        // issue next-tile staging early (async, drains at end-of-iter barrier)
        if (kt + 1 < NT) {
            const unsigned nb = (cur ^ 1);
            #pragma unroll
            for (int j = 0; j < 4; ++j)
                GLDS16(Kg + (size_t)(kt + 1) * 64 * HD + ksrc[j],
                       (char*)Ks + nb * 16384 + kdst[j]);
            #pragma unroll
            for (int j = 0; j < 3; ++j)
                GLDS16(Vg + (size_t)(kt + 1) * 64 + vsrc[j],
                       (char*)Vs + nb * 12288 + vdst[j]);
        }

        // ---- QK^T: S^T[kappa][q] ----
        f32x16 s[2] = {};
        __builtin_amdgcn_s_setprio(1);
        #pragma unroll
        for (int ks = 0; ks < 2; ++ks) {
            const int rr = ks * 32 + c31;
            #pragma unroll
            for (int st = 0; st < 6; ++st) {
                const int slot = (2 * st + lh) ^ (rr & 7);
                bf16x8 ka = *reinterpret_cast<const bf16x8*>(
                    (const char*)Ks + cur * 16384 + rr * 256 + slot * 16);
                s[ks] = __builtin_amdgcn_mfma_f32_32x32x16_bf16(ka, qb_[st], s[ks], 0, 0, 0);
            }
        }
        __builtin_amdgcn_s_setprio(0);

        // ---- online softmax (q lane-local; cross-half via permlane32_swap) ----
        float tm = s[0][0];
        #pragma unroll
        for (int ks = 0; ks < 2; ++ks)
            #pragma unroll
            for (int r = 0; r < 16; ++r) tm = fmaxf(tm, s[ks][r]);
        {
            float ex = tm;
            asm volatile("" : "+v"(ex));   // opaque copy: force distinct reg
            asm("v_permlane32_swap_b32 %0, %1" : "+v"(ex), "+v"(tm));
            tm = fmaxf(tm, ex);
        }
        if (__any(tm > m_r + 8.f)) {       // defer-rescale (T13), THR=8 -> P <= 256
            const float mn = fmaxf(m_r, tm);
            const float al = __builtin_amdgcn_exp2f(m_r - mn);
            l_r *= al; m_r = mn;
            #pragma unroll
            for (int r = 0; r < 16; ++r) {
                const float ar = __shfl(al, (r & 3) + 8 * (r >> 2) + 4 * lh, 64);
                acc[0][r] *= ar; acc[1][r] *= ar; acc[2][r] *= ar;
            }
        }
        float ps = 0.f;
        #pragma unroll
        for (int ks = 0; ks < 2; ++ks)
            #pragma unroll
            for (int r = 0; r < 16; ++r) {
                const float p = __builtin_amdgcn_exp2f(s[ks][r] - m_r);
                s[ks][r] = p;
                ps += p;
            }
        {
            float ex = ps;
            asm volatile("" : "+v"(ex));
            asm("v_permlane32_swap_b32 %0, %1" : "+v"(ex), "+v"(ps));
            ps += ex;
        }
        l_r += ps;

        // ---- pack P to bf16 pairs: up[ks][quad][j] = pack(s[4q+2j], s[4q+2j+1]) ----
        unsigned up[2][4][2];
        #pragma unroll
        for (int ks = 0; ks < 2; ++ks)
            #pragma unroll
            for (int qd = 0; qd < 4; ++qd)
                #pragma unroll
                for (int j = 0; j < 2; ++j)
                    asm("v_cvt_pk_bf16_f32 %0, %1, %2"
                        : "=v"(up[ks][qd][j])
                        : "v"(s[ks][4 * qd + 2 * j]), "v"(s[ks][4 * qd + 2 * j + 1]));

        // ---- PV: acc[dt] += P(A) x V(B); A-frag via 2 permlane32_swap per 16-k ----
        #pragma unroll
        for (int kc = 0; kc < 4; ++kc) {
            const int ks = kc >> 1, cp = kc & 1;
            unsigned x0 = up[ks][2 * cp][0],     x1 = up[ks][2 * cp][1];
            unsigned y0 = up[ks][2 * cp + 1][0], y1 = up[ks][2 * cp + 1][1];
            asm("v_permlane32_swap_b32 %0, %1" : "+v"(x0), "+v"(y0));
            asm("v_permlane32_swap_b32 %0, %1" : "+v"(x1), "+v"(y1));
            u32x4 pw; pw[0] = x0; pw[1] = x1; pw[2] = y0; pw[3] = y1;
            const bf16x8 pa = __builtin_bit_cast(bf16x8, pw);
            __builtin_amdgcn_s_setprio(1);
            #pragma unroll
            for (int dt = 0; dt < 3; ++dt) {
                const int dd = dt * 32 + c31;
                const int slot = (2 * kc + lh) ^ (dd & 7);
                bf16x8 vb = *reinterpret_cast<const bf16x8*>(
                    (const char*)Vs + cur * 12288 + dd * 128 + slot * 16);
                acc[dt] = __builtin_amdgcn_mfma_f32_32x32x16_bf16(pa, vb, acc[dt], 0, 0, 0);
            }
            __builtin_amdgcn_s_setprio(0);
        }

        __syncthreads();   // drains glds (vmcnt 0): next buffer ready; guards reuse
    }

    // epilogue: D rows q_local=(r&3)+8*(r>>2)+4*lh, cols d=32*dt+c31 (coalesced)
    const float inv = 1.0f / l_r;
    #pragma unroll
    for (int r = 0; r < 16; ++r) {
        const int ql = (r & 3) + 8 * (r >> 2) + 4 * lh;
        const float ir = __shfl(inv, ql, 64);
        const int q = q0 + ql;
        float* dst = out + ((size_t)(b * SEQ + q)) * DM + hd * HD;
        #pragma unroll
        for (int dt = 0; dt < 3; ++dt)
            dst[dt * 32 + c31] = acc[dt][r] * ir;
    }
}

extern "C" void kernel_launch(void* const* d_in, const int* in_sizes, int n_in,
                              void* d_out, int out_size, void* d_ws, size_t ws_size,
                              hipStream_t stream) {
    const float* hidden = (const float*)d_in[0];
    const float* kv     = (const float*)d_in[1];
    const float* Wq     = (const float*)d_in[2];
    const float* Wk     = (const float*)d_in[3];
    const float* Wv     = (const float*)d_in[4];
    float* out = (float*)d_out;

    // workspace layout (bf16): Wt_q, Wt_k, Wt_v, Q, K, Vt  (~41.3 MB total)
    __bf16* Wt_q = (__bf16*)d_ws;
    __bf16* Wt_k = Wt_q + WELEM;
    __bf16* Wt_v = Wt_k + WELEM;
    __bf16* Qb   = Wt_v + WELEM;
    __bf16* Kb   = Qb + (size_t)BATCH * NH * SEQ * HD;
    __bf16* Vtb  = Kb + (size_t)BATCH * NH * SEQ * HD;

    transpose_w3<<<3 * (WELEM / 256), 256, 0, stream>>>(Wq, Wk, Wv, Wt_q, Wt_k, Wt_v);

    const float qscale = 0.10206207261596575f * 1.4426950408889634f; // 1/sqrt(96)*log2(e)
    dim3 pgrid(BATCH * SEQ / 64, DM / 64);
    proj_gemm<<<pgrid, 256, 0, stream>>>(hidden, Wt_q, Qb, 0, qscale);
    proj_gemm<<<pgrid, 256, 0, stream>>>(kv,     Wt_k, Kb, 0, 1.0f);
    proj_gemm<<<pgrid, 256, 0, stream>>>(kv,     Wt_v, Vtb, 1, 1.0f);

    attn_kernel<<<512, 256, 0, stream>>>(Qb, Kb, Vtb, out);
}

// Round 5
// 209.180 us; speedup vs baseline: 1.5922x; 1.0648x over previous
//
#include <hip/hip_runtime.h>
#include <hip/hip_bf16.h>

// Multihead cross-attention, B=2, LQ=LK=4096, D=768, H=8, dh=96.
// Pipeline: Wt transpose + X f32->bf16 convert -> QKV proj GEMMs (128^2 tile,
// global_load_lds dbuf, XOR-swizzled LDS) -> flash attn (32x32x16, P in-reg).

typedef __bf16 bf16x8 __attribute__((ext_vector_type(8)));
typedef __bf16 bf16x4 __attribute__((ext_vector_type(4)));
typedef float  f32x4  __attribute__((ext_vector_type(4)));
typedef float  f32x16 __attribute__((ext_vector_type(16)));
typedef unsigned u32x4 __attribute__((ext_vector_type(4)));

#define DM   768
#define NH   8
#define HD   96
#define SEQ  4096
#define BATCH 2
#define WELEM (DM*DM)   // 589824
#define XELEM (BATCH*SEQ*DM)  // 6291456

#define GLDS16(gp, lp) __builtin_amdgcn_global_load_lds( \
    (const __attribute__((address_space(1))) void*)(gp), \
    (__attribute__((address_space(3))) void*)(lp), 16, 0, 0)

// ---------------- W transpose + f32->bf16 (one launch, 3 matrices) -------------
__global__ __launch_bounds__(256) void transpose_w3(
    const float* __restrict__ Wq, const float* __restrict__ Wk, const float* __restrict__ Wv,
    __bf16* __restrict__ Tq, __bf16* __restrict__ Tk, __bf16* __restrict__ Tv)
{
    int tid = blockIdx.x * 256 + threadIdx.x;   // 3*589824 total
    int which = tid / WELEM;                    // uniform per block (2304 blocks each)
    int e = tid - which * WELEM;
    int k = e / DM, n = e - k * DM;             // W[k][n], read coalesced
    const float* W = (which == 0) ? Wq : (which == 1) ? Wk : Wv;
    __bf16* T      = (which == 0) ? Tq : (which == 1) ? Tk : Tv;
    T[n * DM + k] = (__bf16)W[e];
}

// ---------------- X f32 -> bf16 streaming convert (hidden & kv) ----------------
__global__ __launch_bounds__(256) void convert_x(
    const float* __restrict__ X0, const float* __restrict__ X1,
    __bf16* __restrict__ Y0, __bf16* __restrict__ Y1)
{
    const float* X = blockIdx.y ? X1 : X0;
    __bf16* Y      = blockIdx.y ? Y1 : Y0;
    const size_t i = ((size_t)blockIdx.x * 256 + threadIdx.x) * 8;
    float4 lo = *reinterpret_cast<const float4*>(X + i);
    float4 hi = *reinterpret_cast<const float4*>(X + i + 4);
    bf16x8 v;
    v[0]=(__bf16)lo.x; v[1]=(__bf16)lo.y; v[2]=(__bf16)lo.z; v[3]=(__bf16)lo.w;
    v[4]=(__bf16)hi.x; v[5]=(__bf16)hi.y; v[6]=(__bf16)hi.z; v[7]=(__bf16)hi.w;
    *reinterpret_cast<bf16x8*>(Y + i) = v;
}

// ---------------- projection GEMM: Y = Xb @ Wt^T (both bf16) ----------------
// 128x128 tile, BK=64, 4 waves x (64x64), glds width-16 dbuf staging,
// 16B-chunk XOR swizzle (slot = chunk ^ (row&7)) on source AND read.
// mode 0: Y[b][h][l][d] = acc*scale;  mode 1: Y[b][h][d][l] = acc (V transposed).
__global__ __launch_bounds__(256, 2) void proj_gemm128(
    const __bf16* __restrict__ Xb, const __bf16* __restrict__ Wt,
    __bf16* __restrict__ Y, int mode, float scale)
{
    __shared__ __bf16 As[2][128][64];   // 32 KB
    __shared__ __bf16 Bs[2][128][64];   // 32 KB

    const int t = threadIdx.x;
    const int l = t & 63;
    const int w = t >> 6;
    const int ln = l & 15, g = l >> 4;
    const int wm = w >> 1, wn = w & 1;

    // XCD-chunked mapping: 384 blocks, xcd = id&7 owns m-tiles [8x, 8x+8)
    const int id = blockIdx.x;
    const int xcd = id & 7, c = id >> 3;          // c in 0..47
    const int m0 = (xcd * 8 + c / 6) * 128;
    const int n0 = (c % 6) * 128;

    // staging geometry: 8 chunks/row, 4 glds rounds per matrix
    size_t asrc[4], bsrc[4]; unsigned sdst[4];
    #pragma unroll
    for (int j = 0; j < 4; ++j) {
        const int cid = j * 256 + t;              // 0..1023
        const int r = cid >> 3, cc = cid & 7, cs = cc ^ (r & 7);
        asrc[j] = (size_t)(m0 + r) * DM + cs * 8;
        bsrc[j] = (size_t)(n0 + r) * DM + cs * 8;
        sdst[j] = cid * 16;
    }

    f32x4 acc[4][4] = {};

    // prologue: stage tile 0 -> buf 0
    #pragma unroll
    for (int j = 0; j < 4; ++j) GLDS16(Xb + asrc[j], (char*)As + sdst[j]);
    #pragma unroll
    for (int j = 0; j < 4; ++j) GLDS16(Wt + bsrc[j], (char*)Bs + sdst[j]);
    __syncthreads();

    const int NKT = DM / 64;   // 12
    for (int kt = 0; kt < NKT; ++kt) {
        const int cur = kt & 1;
        if (kt + 1 < NKT) {
            const unsigned nb = (cur ^ 1) * 16384u;
            const size_t k0n = (size_t)(kt + 1) * 64;
            #pragma unroll
            for (int j = 0; j < 4; ++j) GLDS16(Xb + k0n + asrc[j], (char*)As + nb + sdst[j]);
            #pragma unroll
            for (int j = 0; j < 4; ++j) GLDS16(Wt + k0n + bsrc[j], (char*)Bs + nb + sdst[j]);
        }

        #pragma unroll
        for (int kk = 0; kk < 2; ++kk) {
            bf16x8 a[4], b[4];
            #pragma unroll
            for (int ms = 0; ms < 4; ++ms) {
                const int row = wm * 64 + ms * 16 + ln;
                const int slot = (kk * 4 + g) ^ (row & 7);
                a[ms] = *reinterpret_cast<const bf16x8*>(
                    (const char*)As + cur * 16384 + row * 128 + slot * 16);
            }
            #pragma unroll
            for (int ns = 0; ns < 4; ++ns) {
                const int row = wn * 64 + ns * 16 + ln;
                const int slot = (kk * 4 + g) ^ (row & 7);
                b[ns] = *reinterpret_cast<const bf16x8*>(
                    (const char*)Bs + cur * 16384 + row * 128 + slot * 16);
            }
            #pragma unroll
            for (int ms = 0; ms < 4; ++ms)
                #pragma unroll
                for (int ns = 0; ns < 4; ++ns)
                    acc[ms][ns] = __builtin_amdgcn_mfma_f32_16x16x32_bf16(
                        a[ms], b[ns], acc[ms][ns], 0, 0, 0);
        }
        __syncthreads();   // drains glds (vmcnt 0): next buffer ready; guards reuse
    }

    // epilogue: D layout col=ln, row=4g+r  [m89]
    #pragma unroll
    for (int ms = 0; ms < 4; ++ms) {
        #pragma unroll
        for (int ns = 0; ns < 4; ++ns) {
            const int col = n0 + wn * 64 + ns * 16 + ln;
            const int h = col / HD, d = col - h * HD;
            const int row_base = m0 + wm * 64 + ms * 16 + 4 * g;
            if (mode == 0) {
                #pragma unroll
                for (int r = 0; r < 4; ++r) {
                    const int row = row_base + r;
                    const int b_ = row >> 12, q = row & (SEQ - 1);
                    Y[(((size_t)(b_ * NH + h) * SEQ) + q) * HD + d] =
                        (__bf16)(acc[ms][ns][r] * scale);
                }
            } else {
                const int b_ = row_base >> 12, kq = row_base & (SEQ - 1);
                bf16x4 v;
                #pragma unroll
                for (int r = 0; r < 4; ++r) v[r] = (__bf16)acc[ms][ns][r];
                *reinterpret_cast<bf16x4*>(
                    &Y[((size_t)(b_ * NH + h) * HD + d) * SEQ + kq]) = v;
            }
        }
    }
}

// ---------------- flash attention: 32x32x16 MFMA, P in registers ----------------
// 1D grid 512 blocks (XCD-chunked swizzle), 4 waves x 32 q-rows, KBLK=64.
// S^T = mfma(K, Q): D col = q = lane&31 (lane-local softmax),
//                   row = kappa = (r&3)+8*(r>>2)+4*(lane>>5).
// PV: ctx = mfma(P, V): A=P built in-register (cvt_pk + permlane32_swap).
__global__ __launch_bounds__(256, 2) void attn_kernel(
    const __bf16* __restrict__ Q, const __bf16* __restrict__ K,
    const __bf16* __restrict__ Vt, float* __restrict__ out)
{
    __shared__ __bf16 Ks[2][64][128];  // 2x16KB, rows padded 96->128 (16 chunks, XOR r&7)
    __shared__ __bf16 Vs[2][96][64];   // 2x12KB, 8 chunks/row, XOR d&7

    const int t = threadIdx.x;
    const int l = t & 63;
    const int w = t >> 6;
    const int lh = l >> 5;            // lane half (0/1)
    const int c31 = l & 31;

    // XCD-chunked swizzle: 512 blocks, XCD x owns bh {2x, 2x+1}
    const int swz = (blockIdx.x & 7) * 64 + (blockIdx.x >> 3);
    const int bh = swz >> 5;          // 0..15
    const int qb = swz & 31;          // 0..31
    const int b = bh >> 3, hd = bh & 7;
    const int q0 = qb * 128 + w * 32;

    const size_t base = (size_t)bh * SEQ * HD;
    const __bf16* Kg = K + base;
    const __bf16* Vg = Vt + base;

    // staging geometry: K tile 64 rows x 16 chunks (12 valid, 4 dup->chunk0),
    //                   V tile 96 rows x 8 chunks. glds dest = uniform base + 16*lane.
    size_t ksrc[4], vsrc[3];
    unsigned kdst[4], vdst[3];
    #pragma unroll
    for (int j = 0; j < 4; ++j) {
        const int cid = (w * 4 + j) * 64 + l;        // 0..1023
        const int r = cid >> 4, cc = cid & 15;
        int cs = cc ^ (r & 7); if (cs >= 12) cs = 0; // pad chunks -> dup chunk 0 (L2 hit)
        ksrc[j] = (size_t)r * HD + cs * 8;
        kdst[j] = (w * 4 + j) * 1024;
    }
    #pragma unroll
    for (int j = 0; j < 3; ++j) {
        const int cid = (w * 3 + j) * 64 + l;        // 0..767
        const int d = cid >> 3, cc = cid & 7;
        const int cs = cc ^ (d & 7);
        vsrc[j] = (size_t)d * SEQ + cs * 8;
        vdst[j] = (w * 3 + j) * 1024;
    }

    // Q B-fragments (col = q = lane&31, k(d) = 16*st + 8*lh + e), in registers
    bf16x8 qb_[6];
    #pragma unroll
    for (int st = 0; st < 6; ++st)
        qb_[st] = *reinterpret_cast<const bf16x8*>(
            &Q[base + (size_t)(q0 + c31) * HD + st * 16 + 8 * lh]);

    f32x16 acc[3] = {};
    float m_r = -1e30f, l_r = 0.f;

    // prologue: stage tile 0 -> buf 0
    #pragma unroll
    for (int j = 0; j < 4; ++j) GLDS16(Kg + ksrc[j], (char*)Ks + kdst[j]);
    #pragma unroll
    for (int j = 0; j < 3; ++j) GLDS16(Vg + vsrc[j], (char*)Vs + vdst[j]);
    __syncthreads();

    const int NT = SEQ / 64;
    for (int kt = 0; kt < NT; ++kt) {
        const int cur = kt & 1;

        // issue next-tile staging early (async, drains at end-of-iter barrier)
        if (kt + 1 < NT) {
            const unsigned nb = (cur ^ 1);
            #pragma unroll
            for (int j = 0; j < 4; ++j)
                GLDS16(Kg + (size_t)(kt + 1) * 64 * HD + ksrc[j],
                       (char*)Ks + nb * 16384 + kdst[j]);
            #pragma unroll
            for (int j = 0; j < 3; ++j)
                GLDS16(Vg + (size_t)(kt + 1) * 64 + vsrc[j],
                       (char*)Vs + nb * 12288 + vdst[j]);
        }

        // ---- QK^T: S^T[kappa][q] ----
        f32x16 s[2] = {};
        __builtin_amdgcn_s_setprio(1);
        #pragma unroll
        for (int ks = 0; ks < 2; ++ks) {
            const int rr = ks * 32 + c31;
            #pragma unroll
            for (int st = 0; st < 6; ++st) {
                const int slot = (2 * st + lh) ^ (rr & 7);
                bf16x8 ka = *reinterpret_cast<const bf16x8*>(
                    (const char*)Ks + cur * 16384 + rr * 256 + slot * 16);
                s[ks] = __builtin_amdgcn_mfma_f32_32x32x16_bf16(ka, qb_[st], s[ks], 0, 0, 0);
            }
        }
        __builtin_amdgcn_s_setprio(0);

        // ---- online softmax (q lane-local; cross-half via permlane32_swap) ----
        float tm = s[0][0];
        #pragma unroll
        for (int ks = 0; ks < 2; ++ks)
            #pragma unroll
            for (int r = 0; r < 16; ++r) tm = fmaxf(tm, s[ks][r]);
        {
            float ex = tm;
            asm volatile("" : "+v"(ex));   // opaque copy: force distinct reg
            asm("v_permlane32_swap_b32 %0, %1" : "+v"(ex), "+v"(tm));
            tm = fmaxf(tm, ex);
        }
        if (__any(tm > m_r + 8.f)) {       // defer-rescale (T13), THR=8 -> P <= 256
            const float mn = fmaxf(m_r, tm);
            const float al = __builtin_amdgcn_exp2f(m_r - mn);
            l_r *= al; m_r = mn;
            #pragma unroll
            for (int r = 0; r < 16; ++r) {
                const float ar = __shfl(al, (r & 3) + 8 * (r >> 2) + 4 * lh, 64);
                acc[0][r] *= ar; acc[1][r] *= ar; acc[2][r] *= ar;
            }
        }
        float ps = 0.f;
        #pragma unroll
        for (int ks = 0; ks < 2; ++ks)
            #pragma unroll
            for (int r = 0; r < 16; ++r) {
                const float p = __builtin_amdgcn_exp2f(s[ks][r] - m_r);
                s[ks][r] = p;
                ps += p;
            }
        {
            float ex = ps;
            asm volatile("" : "+v"(ex));
            asm("v_permlane32_swap_b32 %0, %1" : "+v"(ex), "+v"(ps));
            ps += ex;
        }
        l_r += ps;

        // ---- pack P to bf16 pairs: up[ks][quad][j] = pack(s[4q+2j], s[4q+2j+1]) ----
        unsigned up[2][4][2];
        #pragma unroll
        for (int ks = 0; ks < 2; ++ks)
            #pragma unroll
            for (int qd = 0; qd < 4; ++qd)
                #pragma unroll
                for (int j = 0; j < 2; ++j)
                    asm("v_cvt_pk_bf16_f32 %0, %1, %2"
                        : "=v"(up[ks][qd][j])
                        : "v"(s[ks][4 * qd + 2 * j]), "v"(s[ks][4 * qd + 2 * j + 1]));

        // ---- PV: acc[dt] += P(A) x V(B); A-frag via 2 permlane32_swap per 16-k ----
        #pragma unroll
        for (int kc = 0; kc < 4; ++kc) {
            const int ks = kc >> 1, cp = kc & 1;
            unsigned x0 = up[ks][2 * cp][0],     x1 = up[ks][2 * cp][1];
            unsigned y0 = up[ks][2 * cp + 1][0], y1 = up[ks][2 * cp + 1][1];
            asm("v_permlane32_swap_b32 %0, %1" : "+v"(x0), "+v"(y0));
            asm("v_permlane32_swap_b32 %0, %1" : "+v"(x1), "+v"(y1));
            u32x4 pw; pw[0] = x0; pw[1] = x1; pw[2] = y0; pw[3] = y1;
            const bf16x8 pa = __builtin_bit_cast(bf16x8, pw);
            __builtin_amdgcn_s_setprio(1);
            #pragma unroll
            for (int dt = 0; dt < 3; ++dt) {
                const int dd = dt * 32 + c31;
                const int slot = (2 * kc + lh) ^ (dd & 7);
                bf16x8 vb = *reinterpret_cast<const bf16x8*>(
                    (const char*)Vs + cur * 12288 + dd * 128 + slot * 16);
                acc[dt] = __builtin_amdgcn_mfma_f32_32x32x16_bf16(pa, vb, acc[dt], 0, 0, 0);
            }
            __builtin_amdgcn_s_setprio(0);
        }

        __syncthreads();   // drains glds (vmcnt 0): next buffer ready; guards reuse
    }

    // epilogue: D rows q_local=(r&3)+8*(r>>2)+4*lh, cols d=32*dt+c31 (coalesced)
    const float inv = 1.0f / l_r;
    #pragma unroll
    for (int r = 0; r < 16; ++r) {
        const int ql = (r & 3) + 8 * (r >> 2) + 4 * lh;
        const float ir = __shfl(inv, ql, 64);
        const int q = q0 + ql;
        float* dst = out + ((size_t)(b * SEQ + q)) * DM + hd * HD;
        #pragma unroll
        for (int dt = 0; dt < 3; ++dt)
            dst[dt * 32 + c31] = acc[dt][r] * ir;
    }
}

extern "C" void kernel_launch(void* const* d_in, const int* in_sizes, int n_in,
                              void* d_out, int out_size, void* d_ws, size_t ws_size,
                              hipStream_t stream) {
    const float* hidden = (const float*)d_in[0];
    const float* kv     = (const float*)d_in[1];
    const float* Wq     = (const float*)d_in[2];
    const float* Wk     = (const float*)d_in[3];
    const float* Wv     = (const float*)d_in[4];
    float* out = (float*)d_out;

    // workspace layout (bf16): Wt_q, Wt_k, Wt_v, Q, K, Vt  (~41.3 MB total)
    __bf16* Wt_q = (__bf16*)d_ws;
    __bf16* Wt_k = Wt_q + WELEM;
    __bf16* Wt_v = Wt_k + WELEM;
    __bf16* Qb   = Wt_v + WELEM;
    __bf16* Kb   = Qb + (size_t)BATCH * NH * SEQ * HD;
    __bf16* Vtb  = Kb + (size_t)BATCH * NH * SEQ * HD;

    // converted X lives in d_out (25.17 MB = exactly out bytes); consumed by the
    // proj GEMMs, then attn overwrites d_out with the final f32 result.
    __bf16* Xh_bf  = (__bf16*)d_out;
    __bf16* Xkv_bf = Xh_bf + XELEM;

    transpose_w3<<<3 * (WELEM / 256), 256, 0, stream>>>(Wq, Wk, Wv, Wt_q, Wt_k, Wt_v);
    convert_x<<<dim3(XELEM / 8 / 256, 2), 256, 0, stream>>>(hidden, kv, Xh_bf, Xkv_bf);

    const float qscale = 0.10206207261596575f * 1.4426950408889634f; // 1/sqrt(96)*log2(e)
    proj_gemm128<<<384, 256, 0, stream>>>(Xh_bf,  Wt_q, Qb,  0, qscale);
    proj_gemm128<<<384, 256, 0, stream>>>(Xkv_bf, Wt_k, Kb,  0, 1.0f);
    proj_gemm128<<<384, 256, 0, stream>>>(Xkv_bf, Wt_v, Vtb, 1, 1.0f);

    attn_kernel<<<512, 256, 0, stream>>>(Qb, Kb, Vtb, out);
}